// Round 2
// baseline (230.251 us; speedup 1.0000x reference)
//
#include <hip/hip_runtime.h>
#include <hip/hip_bf16.h>

// StochasticEnsemble: hard-routed 8-expert MLP.
// Round 11: identical to round 10 (bench infra failed; resubmitting for
// measurement). gemm2 re-tiled 128x128 -> 128x64 (grid 576 -> 1152 blocks,
// LDS 64.5 -> 48.5 KB -> 3 blocks/CU). Counters showed the 128x128 config
// was latency/occupancy-bound (MfmaUtil 9.7, VALU 7.4, HBM 21%, occ 16.5%):
// 2.25 blocks/CU of work with a 2-block LDS cap left ~2 waves/SIMD to hide
// the per-iter barrier vmcnt(0) drain on L3-latency W2 loads. Same fix that
// cured gemm1's starvation in round 9. B staging uses gemm1's float2
// vertical-gather pattern; A staging / swizzle / MFMA layout unchanged.

#define BATCH 2048
#define ZD 128
#define HID 1024
#define OUTD 3072
#define NEXP 8
#define MAXTF 24          // max 128-row M-tiles

typedef short bf16x8 __attribute__((ext_vector_type(8)));   // 8 bf16 = 4 VGPRs
typedef float f32x4 __attribute__((ext_vector_type(4)));

// ---- workspace byte layout (ws_size = 384 MiB) ----
// 0        counts[8]
// 64       ntl[1]
// 128      texp[24]
// 256      perm[3072]               -> ends 12544
// 12544    bucket[8*2048]           -> ends 78080
// 78080    zb bf16 [2048*128]       -> ends 602368
// 602368   Hb bf16 [3072*1024]      -> ends 6893824

__global__ __launch_bounds__(256) void route_kernel(const float* __restrict__ z,
                                                    __hip_bfloat16* __restrict__ zb,
                                                    int* counts, int* bucket) {
    __shared__ int lcnt[NEXP];
    __shared__ int gbase[NEXP];
    int t = threadIdx.x;
    if (t < NEXP) lcnt[t] = 0;
    __syncthreads();

    int s = blockIdx.x * 32 + (t >> 3);          // sample
    int li = t & 7;                               // lane-in-sample
    const float* zp = z + (size_t)s * ZD + li * 16;
    float sum = 0.f;
    union { bf16x8 v8; __hip_bfloat16 h[8]; } u0, u1;
#pragma unroll
    for (int i = 0; i < 4; i++) {
        float4 v = ((const float4*)zp)[i];
        sum += floorf(fabsf(v.x) * 1000.0f) + floorf(fabsf(v.y) * 1000.0f) +
               floorf(fabsf(v.z) * 1000.0f) + floorf(fabsf(v.w) * 1000.0f);
        __hip_bfloat16* dst = (i < 2) ? &u0.h[i * 4] : &u1.h[(i - 2) * 4];
        dst[0] = __float2bfloat16(v.x);
        dst[1] = __float2bfloat16(v.y);
        dst[2] = __float2bfloat16(v.z);
        dst[3] = __float2bfloat16(v.w);
    }
    bf16x8* zo = (bf16x8*)(zb + (size_t)s * ZD + li * 16);
    zo[0] = u0.v8;
    zo[1] = u1.v8;

    sum += __shfl_down(sum, 4);
    sum += __shfl_down(sum, 2);
    sum += __shfl_down(sum, 1);
    int e = 0, lpos = 0;
    if (li == 0) {
        e = ((int)sum) & 7;
        lpos = atomicAdd(&lcnt[e], 1);
    }
    __syncthreads();
    if (t < NEXP) gbase[t] = atomicAdd(&counts[t], lcnt[t]);
    __syncthreads();
    if (li == 0) bucket[e * BATCH + gbase[e] + lpos] = s;
}

__global__ void scan_kernel(const int* __restrict__ counts, int* ntl,
                            int* texp, int* perm, const int* __restrict__ bucket) {
    __shared__ int soff[NEXP + 1];
    __shared__ int scnt[NEXP];
    if (threadIdx.x == 0) {
        int o = 0;
        for (int e = 0; e < NEXP; e++) {
            scnt[e] = counts[e];
            soff[e] = o;
            o += (scnt[e] + 127) & ~127;
        }
        soff[NEXP] = o;
        *ntl = o / 128;
    }
    __syncthreads();
    int total = soff[NEXP];
    for (int r = threadIdx.x; r < total; r += blockDim.x) {
        int e = 0;
        while (r >= soff[e + 1]) e++;
        int i = r - soff[e];
        perm[r] = (i < scnt[e]) ? bucket[e * BATCH + i] : -1;
        if ((r & 127) == 0) texp[r / 128] = e;
    }
}

// ---------------- gemm1: 64m x 64n, BK=64, K=128 (2 iters) ----------------
// ~608 blocks. All-thread staging; dbuf; 1 barrier/iter; XOR-chunk LDS.
__global__ __launch_bounds__(256, 4) void gemm1_fast(
    const __hip_bfloat16* __restrict__ zb, const float* __restrict__ W1,
    const float* __restrict__ b1, const int* __restrict__ ntl,
    const int* __restrict__ texp, const int* __restrict__ perm,
    __hip_bfloat16* __restrict__ H) {
    int mt = blockIdx.y;                 // 64-row tile index
    if (mt >= 2 * (*ntl)) return;
    int e = texp[mt >> 1];
    int n0 = blockIdx.x * 64;

    __shared__ __align__(16) __hip_bfloat16 As[2][64 * 64];   // 2 x 8 KB
    __shared__ __align__(16) __hip_bfloat16 Bs[2][64 * 64];   // 2 x 8 KB

    int tid = threadIdx.x;
    int lane = tid & 63, wave = tid >> 6;
    int cc = lane & 15, q = lane >> 4;
    int mw = (wave >> 1) * 32, nw = (wave & 1) * 32;

    // A staging: thread t covers rows rg and rg+32, k-chunk sc
    int sc = tid & 7, rg = tid >> 3;     // rg 0..31
    int r0 = perm[mt * 64 + rg];      if (r0 < 0) r0 = 0;
    int r1 = perm[mt * 64 + rg + 32]; if (r1 < 0) r1 = 0;
    const __hip_bfloat16* Ap0 = zb + (size_t)r0 * ZD + sc * 8;
    const __hip_bfloat16* Ap1 = zb + (size_t)r1 * ZD + sc * 8;
    int awb = rg * 64 + (sc ^ (rg & 7)) * 8;   // row rg+32 -> +2048, same xor

    // B staging: bkc = k-chunk, 2 n per thread (float2 loads, 64B segments)
    int bkc = tid & 7, bn2 = (tid >> 3) * 2;   // bn2 0..62
    const float* Bgf = W1 + (size_t)e * ZD * HID + (size_t)(bkc * 8) * HID + n0 + bn2;
    int bwb[2];
#pragma unroll
    for (int j = 0; j < 2; j++)
        bwb[j] = ((bn2 + j) * 8 + (bkc ^ ((bn2 + j) & 7))) * 8;

    int A0 = (mw + cc) * 64, B0 = (nw + cc) * 64;
    int X0 = (q ^ (cc & 7)) * 8, X1 = ((4 + q) ^ (cc & 7)) * 8;

    float bias[2];
#pragma unroll
    for (int j = 0; j < 2; j++) bias[j] = b1[(size_t)e * HID + n0 + nw + j * 16 + cc];

    f32x4 zero4 = {0.f, 0.f, 0.f, 0.f};
    f32x4 acc[2][2];
#pragma unroll
    for (int i = 0; i < 2; i++)
#pragma unroll
        for (int j = 0; j < 2; j++) acc[i][j] = zero4;

    bf16x8 ga0 = *(const bf16x8*)Ap0;
    bf16x8 ga1 = *(const bf16x8*)Ap1;
    float2 braw[8];
#pragma unroll
    for (int i = 0; i < 8; i++) braw[i] = *(const float2*)(Bgf + (size_t)i * HID);

#pragma unroll
    for (int it = 0; it < 2; ++it) {
        __hip_bfloat16* Ac = As[it];
        __hip_bfloat16* Bc = Bs[it];
        union { bf16x8 v8; __hip_bfloat16 h[8]; } gbv[2];
#pragma unroll
        for (int i = 0; i < 8; i++) {
            gbv[0].h[i] = __float2bfloat16(braw[i].x);
            gbv[1].h[i] = __float2bfloat16(braw[i].y);
        }
        *(bf16x8*)(Ac + awb) = ga0;
        *(bf16x8*)(Ac + awb + 2048) = ga1;
#pragma unroll
        for (int j = 0; j < 2; j++) *(bf16x8*)(Bc + bwb[j]) = gbv[j].v8;
        if (it == 0) {
            ga0 = *(const bf16x8*)(Ap0 + 64);
            ga1 = *(const bf16x8*)(Ap1 + 64);
#pragma unroll
            for (int i = 0; i < 8; i++)
                braw[i] = *(const float2*)(Bgf + (size_t)(64 + i) * HID);
        }
        __syncthreads();
#pragma unroll
        for (int kh = 0; kh < 2; ++kh) {
            int X = kh ? X1 : X0;
            bf16x8 af[2], bfr[2];
#pragma unroll
            for (int i = 0; i < 2; i++) af[i] = *(const bf16x8*)(Ac + A0 + i * 1024 + X);
#pragma unroll
            for (int j = 0; j < 2; j++) bfr[j] = *(const bf16x8*)(Bc + B0 + j * 1024 + X);
#pragma unroll
            for (int i = 0; i < 2; i++)
#pragma unroll
                for (int j = 0; j < 2; j++)
                    acc[i][j] = __builtin_amdgcn_mfma_f32_16x16x32_bf16(af[i], bfr[j],
                                                                        acc[i][j], 0, 0, 0);
        }
    }
#pragma unroll
    for (int i = 0; i < 2; i++)
#pragma unroll
        for (int r = 0; r < 4; r++) {
            int m = mw + i * 16 + q * 4 + r;
            __hip_bfloat16* hp = H + (size_t)(mt * 64 + m) * HID + n0 + nw + cc;
#pragma unroll
            for (int j = 0; j < 2; j++)
                hp[j * 16] = __float2bfloat16(fmaxf(acc[i][j][r] + bias[j], 0.f));
        }
}

// ---------------- gemm2: 128m x 64n, BK=64 ----------------
// Grid (48, MAXTF) = 1152 blocks (4.5/CU of work); LDS 48.5 KB -> 3 blocks/CU
// resident (12 waves/CU, was 8). All-thread staging, distance-1 register
// prefetch, convert deferred past the MFMA phase, ONE barrier per iter,
// 2 LDS buffers. Wave tile 64x32 (acc[4][2]); B staged via gemm1's float2
// vertical-gather (8 k-rows x 2 n per thread, 64B segments).
__global__ __launch_bounds__(256, 3) void gemm2_fast(
    const __hip_bfloat16* __restrict__ H, const float* __restrict__ W2,
    const float* __restrict__ b2, const int* __restrict__ ntl,
    const int* __restrict__ texp, const int* __restrict__ perm,
    float* __restrict__ out) {
    int mt = blockIdx.y;
    if (mt >= *ntl) return;
    int e = texp[mt];
    int n0 = blockIdx.x * 64;

    __shared__ __align__(16) __hip_bfloat16 As[2][128 * 64];   // 2 x 16 KB
    __shared__ __align__(16) __hip_bfloat16 Bs[2][64 * 64];    // 2 x 8 KB
    __shared__ int rows_s[128];

    int tid = threadIdx.x;
    if (tid < 128) rows_s[tid] = perm[mt * 128 + tid];

    int lane = tid & 63, wave = tid >> 6;
    int cc = lane & 15, q = lane >> 4;
    int mw = (wave >> 1) * 64, nw = (wave & 1) * 32;

    // A staging: thread covers rows sr + p*32 (p=0..3), k-chunk sc
    int sr = tid >> 3, sc = tid & 7;
    int awbase = sr * 64 + (sc ^ (sr & 7)) * 8;     // + p*2048
    const __hip_bfloat16* Ag = H + ((size_t)mt * 128 + sr) * HID + sc * 8;

    // B staging: bkc = k-chunk (8 rows), 2 n per thread (float2, 64B segments)
    int bkc = tid & 7, bn2 = (tid >> 3) * 2;        // bn2 0..62
    const float* Bgf = W2 + (size_t)e * HID * OUTD + (size_t)(bkc * 8) * OUTD + n0 + bn2;
    int bwb[2];
#pragma unroll
    for (int j = 0; j < 2; j++)
        bwb[j] = (bn2 + j) * 64 + (bkc ^ ((bn2 + j) & 7)) * 8;

    int A0 = (mw + cc) * 64, B0 = (nw + cc) * 64;
    int X0 = (q ^ (cc & 7)) * 8, X1 = ((4 + q) ^ (cc & 7)) * 8;

    float bias[2];
#pragma unroll
    for (int j = 0; j < 2; j++) bias[j] = b2[(size_t)e * OUTD + n0 + nw + j * 16 + cc];

    f32x4 zero4 = {0.f, 0.f, 0.f, 0.f};
    f32x4 acc[4][2];
#pragma unroll
    for (int i = 0; i < 4; i++)
#pragma unroll
        for (int j = 0; j < 2; j++) acc[i][j] = zero4;

    bf16x8 ga[4];
    float2 braw[8];
#pragma unroll
    for (int p = 0; p < 4; p++) ga[p] = *(const bf16x8*)(Ag + (size_t)p * 32 * HID);
#pragma unroll
    for (int i = 0; i < 8; i++) braw[i] = *(const float2*)(Bgf + (size_t)i * OUTD);

    const int NIT = HID / 64;   // 16
    for (int it = 0; it < NIT; ++it) {
        __hip_bfloat16* Ac = As[it & 1];
        __hip_bfloat16* Bc = Bs[it & 1];
        union { bf16x8 v8; __hip_bfloat16 h[8]; } gb[2];
#pragma unroll
        for (int i = 0; i < 8; i++) {
            gb[0].h[i] = __float2bfloat16(braw[i].x);
            gb[1].h[i] = __float2bfloat16(braw[i].y);
        }
#pragma unroll
        for (int p = 0; p < 4; p++) *(bf16x8*)(Ac + awbase + p * 2048) = ga[p];
#pragma unroll
        for (int j = 0; j < 2; j++) *(bf16x8*)(Bc + bwb[j]) = gb[j].v8;
        if (it + 1 < NIT) {
            int k1 = (it + 1) * 64;
#pragma unroll
            for (int p = 0; p < 4; p++)
                ga[p] = *(const bf16x8*)(Ag + (size_t)p * 32 * HID + k1);
#pragma unroll
            for (int i = 0; i < 8; i++)
                braw[i] = *(const float2*)(Bgf + (size_t)(k1 + i) * OUTD);
        }
        __syncthreads();
#pragma unroll
        for (int kh = 0; kh < 2; ++kh) {
            int X = kh ? X1 : X0;
            bf16x8 af[4], bfr[2];
#pragma unroll
            for (int i = 0; i < 4; i++) af[i] = *(const bf16x8*)(Ac + A0 + i * 1024 + X);
#pragma unroll
            for (int j = 0; j < 2; j++) bfr[j] = *(const bf16x8*)(Bc + B0 + j * 1024 + X);
#pragma unroll
            for (int i = 0; i < 4; i++)
#pragma unroll
                for (int j = 0; j < 2; j++)
                    acc[i][j] = __builtin_amdgcn_mfma_f32_16x16x32_bf16(af[i], bfr[j],
                                                                        acc[i][j], 0, 0, 0);
        }
    }
#pragma unroll
    for (int i = 0; i < 4; i++)
#pragma unroll
        for (int r = 0; r < 4; r++) {
            int m = mw + i * 16 + q * 4 + r;
            int orow = rows_s[m];
            if (orow >= 0) {
                float* op = out + (size_t)orow * OUTD + n0 + nw + cc;
#pragma unroll
                for (int j = 0; j < 2; j++) op[j * 16] = acc[i][j][r] + bias[j];
            }
        }
}

extern "C" void kernel_launch(void* const* d_in, const int* in_sizes, int n_in,
                              void* d_out, int out_size, void* d_ws, size_t ws_size,
                              hipStream_t stream) {
    const float* z  = (const float*)d_in[0];
    const float* W1 = (const float*)d_in[1];
    const float* b1 = (const float*)d_in[2];
    const float* W2 = (const float*)d_in[3];
    const float* b2 = (const float*)d_in[4];
    float* out = (float*)d_out;

    char* ws = (char*)d_ws;
    int* counts = (int*)ws;
    int* ntl    = (int*)(ws + 64);
    int* texp   = (int*)(ws + 128);
    int* perm   = (int*)(ws + 256);
    int* bucket = (int*)(ws + 12544);
    __hip_bfloat16* zb  = (__hip_bfloat16*)(ws + 78080);
    __hip_bfloat16* Hb  = (__hip_bfloat16*)(ws + 602368);

    hipMemsetAsync(counts, 0, 64, stream);
    hipLaunchKernelGGL(route_kernel, dim3(BATCH / 32), dim3(256), 0, stream,
                       z, zb, counts, bucket);
    hipLaunchKernelGGL(scan_kernel, dim3(1), dim3(256), 0, stream,
                       counts, ntl, texp, perm, bucket);
    hipLaunchKernelGGL(gemm1_fast, dim3(HID / 64, 2 * MAXTF), dim3(256), 0, stream,
                       zb, W1, b1, ntl, texp, perm, Hb);
    hipLaunchKernelGGL(gemm2_fast, dim3(OUTD / 64, MAXTF), dim3(256), 0, stream,
                       Hb, W2, b2, ntl, texp, perm, out);
}

// Round 3
// 205.251 us; speedup vs baseline: 1.1218x; 1.1218x over previous
//
#include <hip/hip_runtime.h>
#include <hip/hip_bf16.h>

// StochasticEnsemble: hard-routed 8-expert MLP.
// Round 12: REVERT round-10/11 gemm2 retile (128x64 regressed 61->90 us:
// occupancy rose 16.5->24.4 but MfmaUtil fell 9.7->6.6 — halving MFMA-per-
// barrier hurt more than TLP helped). Back to the measured round-6 geometry
// (128x128, BK=64, acc[4][4], 2 LDS buffers, 1 barrier/iter) with ONE change:
// distance-2 register prefetch (two named register sets, pair-unrolled loop)
// so the L3-latency W2 float4 loads get ~2 iterations to land instead of ~1.
// route/scan/gemm1 identical to the 202-us round-9 baseline.

#define BATCH 2048
#define ZD 128
#define HID 1024
#define OUTD 3072
#define NEXP 8
#define MAXTF 24          // max 128-row M-tiles

typedef short bf16x8 __attribute__((ext_vector_type(8)));   // 8 bf16 = 4 VGPRs
typedef float f32x4 __attribute__((ext_vector_type(4)));

// ---- workspace byte layout (ws_size = 384 MiB) ----
// 0        counts[8]
// 64       ntl[1]
// 128      texp[24]
// 256      perm[3072]               -> ends 12544
// 12544    bucket[8*2048]           -> ends 78080
// 78080    zb bf16 [2048*128]       -> ends 602368
// 602368   Hb bf16 [3072*1024]      -> ends 6893824

__global__ __launch_bounds__(256) void route_kernel(const float* __restrict__ z,
                                                    __hip_bfloat16* __restrict__ zb,
                                                    int* counts, int* bucket) {
    __shared__ int lcnt[NEXP];
    __shared__ int gbase[NEXP];
    int t = threadIdx.x;
    if (t < NEXP) lcnt[t] = 0;
    __syncthreads();

    int s = blockIdx.x * 32 + (t >> 3);          // sample
    int li = t & 7;                               // lane-in-sample
    const float* zp = z + (size_t)s * ZD + li * 16;
    float sum = 0.f;
    union { bf16x8 v8; __hip_bfloat16 h[8]; } u0, u1;
#pragma unroll
    for (int i = 0; i < 4; i++) {
        float4 v = ((const float4*)zp)[i];
        sum += floorf(fabsf(v.x) * 1000.0f) + floorf(fabsf(v.y) * 1000.0f) +
               floorf(fabsf(v.z) * 1000.0f) + floorf(fabsf(v.w) * 1000.0f);
        __hip_bfloat16* dst = (i < 2) ? &u0.h[i * 4] : &u1.h[(i - 2) * 4];
        dst[0] = __float2bfloat16(v.x);
        dst[1] = __float2bfloat16(v.y);
        dst[2] = __float2bfloat16(v.z);
        dst[3] = __float2bfloat16(v.w);
    }
    bf16x8* zo = (bf16x8*)(zb + (size_t)s * ZD + li * 16);
    zo[0] = u0.v8;
    zo[1] = u1.v8;

    sum += __shfl_down(sum, 4);
    sum += __shfl_down(sum, 2);
    sum += __shfl_down(sum, 1);
    int e = 0, lpos = 0;
    if (li == 0) {
        e = ((int)sum) & 7;
        lpos = atomicAdd(&lcnt[e], 1);
    }
    __syncthreads();
    if (t < NEXP) gbase[t] = atomicAdd(&counts[t], lcnt[t]);
    __syncthreads();
    if (li == 0) bucket[e * BATCH + gbase[e] + lpos] = s;
}

__global__ void scan_kernel(const int* __restrict__ counts, int* ntl,
                            int* texp, int* perm, const int* __restrict__ bucket) {
    __shared__ int soff[NEXP + 1];
    __shared__ int scnt[NEXP];
    if (threadIdx.x == 0) {
        int o = 0;
        for (int e = 0; e < NEXP; e++) {
            scnt[e] = counts[e];
            soff[e] = o;
            o += (scnt[e] + 127) & ~127;
        }
        soff[NEXP] = o;
        *ntl = o / 128;
    }
    __syncthreads();
    int total = soff[NEXP];
    for (int r = threadIdx.x; r < total; r += blockDim.x) {
        int e = 0;
        while (r >= soff[e + 1]) e++;
        int i = r - soff[e];
        perm[r] = (i < scnt[e]) ? bucket[e * BATCH + i] : -1;
        if ((r & 127) == 0) texp[r / 128] = e;
    }
}

// ---------------- gemm1: 64m x 64n, BK=64, K=128 (2 iters) ----------------
// ~608 blocks. All-thread staging; dbuf; 1 barrier/iter; XOR-chunk LDS.
__global__ __launch_bounds__(256, 4) void gemm1_fast(
    const __hip_bfloat16* __restrict__ zb, const float* __restrict__ W1,
    const float* __restrict__ b1, const int* __restrict__ ntl,
    const int* __restrict__ texp, const int* __restrict__ perm,
    __hip_bfloat16* __restrict__ H) {
    int mt = blockIdx.y;                 // 64-row tile index
    if (mt >= 2 * (*ntl)) return;
    int e = texp[mt >> 1];
    int n0 = blockIdx.x * 64;

    __shared__ __align__(16) __hip_bfloat16 As[2][64 * 64];   // 2 x 8 KB
    __shared__ __align__(16) __hip_bfloat16 Bs[2][64 * 64];   // 2 x 8 KB

    int tid = threadIdx.x;
    int lane = tid & 63, wave = tid >> 6;
    int cc = lane & 15, q = lane >> 4;
    int mw = (wave >> 1) * 32, nw = (wave & 1) * 32;

    // A staging: thread t covers rows rg and rg+32, k-chunk sc
    int sc = tid & 7, rg = tid >> 3;     // rg 0..31
    int r0 = perm[mt * 64 + rg];      if (r0 < 0) r0 = 0;
    int r1 = perm[mt * 64 + rg + 32]; if (r1 < 0) r1 = 0;
    const __hip_bfloat16* Ap0 = zb + (size_t)r0 * ZD + sc * 8;
    const __hip_bfloat16* Ap1 = zb + (size_t)r1 * ZD + sc * 8;
    int awb = rg * 64 + (sc ^ (rg & 7)) * 8;   // row rg+32 -> +2048, same xor

    // B staging: bkc = k-chunk, 2 n per thread (float2 loads, 64B segments)
    int bkc = tid & 7, bn2 = (tid >> 3) * 2;   // bn2 0..62
    const float* Bgf = W1 + (size_t)e * ZD * HID + (size_t)(bkc * 8) * HID + n0 + bn2;
    int bwb[2];
#pragma unroll
    for (int j = 0; j < 2; j++)
        bwb[j] = ((bn2 + j) * 8 + (bkc ^ ((bn2 + j) & 7))) * 8;

    int A0 = (mw + cc) * 64, B0 = (nw + cc) * 64;
    int X0 = (q ^ (cc & 7)) * 8, X1 = ((4 + q) ^ (cc & 7)) * 8;

    float bias[2];
#pragma unroll
    for (int j = 0; j < 2; j++) bias[j] = b1[(size_t)e * HID + n0 + nw + j * 16 + cc];

    f32x4 zero4 = {0.f, 0.f, 0.f, 0.f};
    f32x4 acc[2][2];
#pragma unroll
    for (int i = 0; i < 2; i++)
#pragma unroll
        for (int j = 0; j < 2; j++) acc[i][j] = zero4;

    bf16x8 ga0 = *(const bf16x8*)Ap0;
    bf16x8 ga1 = *(const bf16x8*)Ap1;
    float2 braw[8];
#pragma unroll
    for (int i = 0; i < 8; i++) braw[i] = *(const float2*)(Bgf + (size_t)i * HID);

#pragma unroll
    for (int it = 0; it < 2; ++it) {
        __hip_bfloat16* Ac = As[it];
        __hip_bfloat16* Bc = Bs[it];
        union { bf16x8 v8; __hip_bfloat16 h[8]; } gbv[2];
#pragma unroll
        for (int i = 0; i < 8; i++) {
            gbv[0].h[i] = __float2bfloat16(braw[i].x);
            gbv[1].h[i] = __float2bfloat16(braw[i].y);
        }
        *(bf16x8*)(Ac + awb) = ga0;
        *(bf16x8*)(Ac + awb + 2048) = ga1;
#pragma unroll
        for (int j = 0; j < 2; j++) *(bf16x8*)(Bc + bwb[j]) = gbv[j].v8;
        if (it == 0) {
            ga0 = *(const bf16x8*)(Ap0 + 64);
            ga1 = *(const bf16x8*)(Ap1 + 64);
#pragma unroll
            for (int i = 0; i < 8; i++)
                braw[i] = *(const float2*)(Bgf + (size_t)(64 + i) * HID);
        }
        __syncthreads();
#pragma unroll
        for (int kh = 0; kh < 2; ++kh) {
            int X = kh ? X1 : X0;
            bf16x8 af[2], bfr[2];
#pragma unroll
            for (int i = 0; i < 2; i++) af[i] = *(const bf16x8*)(Ac + A0 + i * 1024 + X);
#pragma unroll
            for (int j = 0; j < 2; j++) bfr[j] = *(const bf16x8*)(Bc + B0 + j * 1024 + X);
#pragma unroll
            for (int i = 0; i < 2; i++)
#pragma unroll
                for (int j = 0; j < 2; j++)
                    acc[i][j] = __builtin_amdgcn_mfma_f32_16x16x32_bf16(af[i], bfr[j],
                                                                        acc[i][j], 0, 0, 0);
        }
    }
#pragma unroll
    for (int i = 0; i < 2; i++)
#pragma unroll
        for (int r = 0; r < 4; r++) {
            int m = mw + i * 16 + q * 4 + r;
            __hip_bfloat16* hp = H + (size_t)(mt * 64 + m) * HID + n0 + nw + cc;
#pragma unroll
            for (int j = 0; j < 2; j++)
                hp[j * 16] = __float2bfloat16(fmaxf(acc[i][j][r] + bias[j], 0.f));
        }
}

// ---------------- gemm2: 128m x 128n, BK=64 (round-6 geometry) ----------------
// Grid (24, MAXTF) = 576 blocks, 2 blocks/CU (64.5 KB LDS). All-thread staging,
// convert deferred past the MFMA phase, ONE barrier per iter, 2 LDS buffers.
// Round 12: DISTANCE-2 register prefetch — two named register sets (A/B),
// pair-unrolled loop (static indexing only); W2 loads for iter k+2 are issued
// during iter k, giving L3-latency loads ~2 iterations to land.
__global__ __launch_bounds__(256, 2) void gemm2_fast(
    const __hip_bfloat16* __restrict__ H, const float* __restrict__ W2,
    const float* __restrict__ b2, const int* __restrict__ ntl,
    const int* __restrict__ texp, const int* __restrict__ perm,
    float* __restrict__ out) {
    int mt = blockIdx.y;
    if (mt >= *ntl) return;
    int e = texp[mt];
    int n0 = blockIdx.x * 128;

    __shared__ __align__(16) __hip_bfloat16 As[2][128 * 64];   // 2 x 16 KB
    __shared__ __align__(16) __hip_bfloat16 Bs[2][128 * 64];   // 2 x 16 KB
    __shared__ int rows_s[128];

    int tid = threadIdx.x;
    if (tid < 128) rows_s[tid] = perm[mt * 128 + tid];

    int lane = tid & 63, wave = tid >> 6;
    int cc = lane & 15, q = lane >> 4;
    int mw = (wave >> 1) * 64, nw = (wave & 1) * 64;

    // A staging: thread covers rows sr + p*32 (p=0..3), k-chunk sc
    int sr = tid >> 3, sc = tid & 7;
    int awbase = sr * 64 + (sc ^ (sr & 7)) * 8;     // + p*2048
    const __hip_bfloat16* Ag = H + ((size_t)mt * 128 + sr) * HID + sc * 8;

    // B staging: bkc = k-chunk (8 rows), 4 n per thread (float4)
    int bkc = tid & 7, bn = (tid >> 3) * 4;
    const float* Bgf = W2 + (size_t)e * HID * OUTD + (size_t)(bkc * 8) * OUTD + n0 + bn;
    int bwb[4];
#pragma unroll
    for (int j = 0; j < 4; j++)
        bwb[j] = (bn + j) * 64 + ((bkc ^ ((bn + j) & 7))) * 8;

    int A0 = (mw + cc) * 64, B0 = (nw + cc) * 64;
    int X0 = (q ^ (cc & 7)) * 8, X1 = ((4 + q) ^ (cc & 7)) * 8;

    float bias[4];
#pragma unroll
    for (int j = 0; j < 4; j++) bias[j] = b2[(size_t)e * OUTD + n0 + nw + j * 16 + cc];

    f32x4 zero4 = {0.f, 0.f, 0.f, 0.f};
    f32x4 acc[4][4];
#pragma unroll
    for (int i = 0; i < 4; i++)
#pragma unroll
        for (int j = 0; j < 4; j++) acc[i][j] = zero4;

    // Distance-2 prefetch: set A holds k-block (2*itp), set B holds (2*itp+1).
    bf16x8 gaA[4], gaB[4];
    float4 brA[8], brB[8];
#pragma unroll
    for (int p = 0; p < 4; p++) gaA[p] = *(const bf16x8*)(Ag + (size_t)p * 32 * HID);
#pragma unroll
    for (int i = 0; i < 8; i++) brA[i] = *(const float4*)(Bgf + (size_t)i * OUTD);
#pragma unroll
    for (int p = 0; p < 4; p++) gaB[p] = *(const bf16x8*)(Ag + (size_t)p * 32 * HID + 64);
#pragma unroll
    for (int i = 0; i < 8; i++) brB[i] = *(const float4*)(Bgf + (size_t)(64 + i) * OUTD);

    const int NIT = HID / 64;   // 16 (even)
    for (int itp = 0; itp < NIT / 2; ++itp) {
        int kre = itp * 128;                 // reload bases: even -> kre+128, odd -> kre+192
        bool more = (itp < NIT / 2 - 1);

        // ======== even iter (k-block 2*itp): consume set A, LDS buf 0 ========
        {
            union { bf16x8 v8; __hip_bfloat16 h[8]; } gb[4];
#pragma unroll
            for (int i = 0; i < 8; i++) {
                gb[0].h[i] = __float2bfloat16(brA[i].x);
                gb[1].h[i] = __float2bfloat16(brA[i].y);
                gb[2].h[i] = __float2bfloat16(brA[i].z);
                gb[3].h[i] = __float2bfloat16(brA[i].w);
            }
#pragma unroll
            for (int p = 0; p < 4; p++) *(bf16x8*)(As[0] + awbase + p * 2048) = gaA[p];
#pragma unroll
            for (int j = 0; j < 4; j++) *(bf16x8*)(Bs[0] + bwb[j]) = gb[j].v8;
            if (more) {
#pragma unroll
                for (int p = 0; p < 4; p++)
                    gaA[p] = *(const bf16x8*)(Ag + (size_t)p * 32 * HID + kre + 128);
#pragma unroll
                for (int i = 0; i < 8; i++)
                    brA[i] = *(const float4*)(Bgf + (size_t)(kre + 128 + i) * OUTD);
            }
            __syncthreads();
#pragma unroll
            for (int kh = 0; kh < 2; ++kh) {
                int X = kh ? X1 : X0;
                bf16x8 af[4], bfr[4];
#pragma unroll
                for (int i = 0; i < 4; i++) af[i] = *(const bf16x8*)(As[0] + A0 + i * 1024 + X);
#pragma unroll
                for (int j = 0; j < 4; j++) bfr[j] = *(const bf16x8*)(Bs[0] + B0 + j * 1024 + X);
#pragma unroll
                for (int i = 0; i < 4; i++)
#pragma unroll
                    for (int j = 0; j < 4; j++)
                        acc[i][j] = __builtin_amdgcn_mfma_f32_16x16x32_bf16(af[i], bfr[j],
                                                                            acc[i][j], 0, 0, 0);
            }
        }

        // ======== odd iter (k-block 2*itp+1): consume set B, LDS buf 1 ========
        {
            union { bf16x8 v8; __hip_bfloat16 h[8]; } gb[4];
#pragma unroll
            for (int i = 0; i < 8; i++) {
                gb[0].h[i] = __float2bfloat16(brB[i].x);
                gb[1].h[i] = __float2bfloat16(brB[i].y);
                gb[2].h[i] = __float2bfloat16(brB[i].z);
                gb[3].h[i] = __float2bfloat16(brB[i].w);
            }
#pragma unroll
            for (int p = 0; p < 4; p++) *(bf16x8*)(As[1] + awbase + p * 2048) = gaB[p];
#pragma unroll
            for (int j = 0; j < 4; j++) *(bf16x8*)(Bs[1] + bwb[j]) = gb[j].v8;
            if (more) {
#pragma unroll
                for (int p = 0; p < 4; p++)
                    gaB[p] = *(const bf16x8*)(Ag + (size_t)p * 32 * HID + kre + 192);
#pragma unroll
                for (int i = 0; i < 8; i++)
                    brB[i] = *(const float4*)(Bgf + (size_t)(kre + 192 + i) * OUTD);
            }
            __syncthreads();
#pragma unroll
            for (int kh = 0; kh < 2; ++kh) {
                int X = kh ? X1 : X0;
                bf16x8 af[4], bfr[4];
#pragma unroll
                for (int i = 0; i < 4; i++) af[i] = *(const bf16x8*)(As[1] + A0 + i * 1024 + X);
#pragma unroll
                for (int j = 0; j < 4; j++) bfr[j] = *(const bf16x8*)(Bs[1] + B0 + j * 1024 + X);
#pragma unroll
                for (int i = 0; i < 4; i++)
#pragma unroll
                    for (int j = 0; j < 4; j++)
                        acc[i][j] = __builtin_amdgcn_mfma_f32_16x16x32_bf16(af[i], bfr[j],
                                                                            acc[i][j], 0, 0, 0);
            }
        }
    }

#pragma unroll
    for (int i = 0; i < 4; i++)
#pragma unroll
        for (int r = 0; r < 4; r++) {
            int m = mw + i * 16 + q * 4 + r;
            int orow = rows_s[m];
            if (orow >= 0) {
                float* op = out + (size_t)orow * OUTD + n0 + nw + cc;
#pragma unroll
                for (int j = 0; j < 4; j++) op[j * 16] = acc[i][j][r] + bias[j];
            }
        }
}

extern "C" void kernel_launch(void* const* d_in, const int* in_sizes, int n_in,
                              void* d_out, int out_size, void* d_ws, size_t ws_size,
                              hipStream_t stream) {
    const float* z  = (const float*)d_in[0];
    const float* W1 = (const float*)d_in[1];
    const float* b1 = (const float*)d_in[2];
    const float* W2 = (const float*)d_in[3];
    const float* b2 = (const float*)d_in[4];
    float* out = (float*)d_out;

    char* ws = (char*)d_ws;
    int* counts = (int*)ws;
    int* ntl    = (int*)(ws + 64);
    int* texp   = (int*)(ws + 128);
    int* perm   = (int*)(ws + 256);
    int* bucket = (int*)(ws + 12544);
    __hip_bfloat16* zb  = (__hip_bfloat16*)(ws + 78080);
    __hip_bfloat16* Hb  = (__hip_bfloat16*)(ws + 602368);

    hipMemsetAsync(counts, 0, 64, stream);
    hipLaunchKernelGGL(route_kernel, dim3(BATCH / 32), dim3(256), 0, stream,
                       z, zb, counts, bucket);
    hipLaunchKernelGGL(scan_kernel, dim3(1), dim3(256), 0, stream,
                       counts, ntl, texp, perm, bucket);
    hipLaunchKernelGGL(gemm1_fast, dim3(HID / 64, 2 * MAXTF), dim3(256), 0, stream,
                       zb, W1, b1, ntl, texp, perm, Hb);
    hipLaunchKernelGGL(gemm2_fast, dim3(OUTD / 128, MAXTF), dim3(256), 0, stream,
                       Hb, W2, b2, ntl, texp, perm, out);
}

// Round 5
// 203.818 us; speedup vs baseline: 1.1297x; 1.0070x over previous
//
#include <hip/hip_runtime.h>
#include <hip/hip_bf16.h>

// StochasticEnsemble: hard-routed 8-expert MLP.
// Round 14: identical to round 13 (bench infra failed twice; resubmitting).
// Counted-vmcnt barriers (T4): __syncthreads() emits s_waitcnt vmcnt(0)
// before s_barrier, draining the just-issued prefetch loads every phase
// (9120 cyc/phase vs ~1000 cyc of real work at 2 blocks/CU). Fix: replace
// __syncthreads in gemm1/gemm2 with {s_waitcnt lgkmcnt(0); raw s_barrier}
// so prefetched global loads stay in flight across barriers; the compiler's
// register-dep tracking supplies precise counted vmcnt(N) waits where the
// loaded values are consumed. Geometry unchanged from the measured round-6
// optimum (gemm2 128x128 BK=64, gemm1 64x64 BK=64).
// Race audit: phase k+2 writes buf[k&1] only after barrier k+1, whose
// lgkmcnt(0) guarantees every wave's phase-k reads of that buffer drained.

#define BATCH 2048
#define ZD 128
#define HID 1024
#define OUTD 3072
#define NEXP 8
#define MAXTF 24          // max 128-row M-tiles

typedef short bf16x8 __attribute__((ext_vector_type(8)));   // 8 bf16 = 4 VGPRs
typedef float f32x4 __attribute__((ext_vector_type(4)));

// Raw barrier: LDS-write visibility (lgkmcnt 0) but NO vmcnt drain, so
// in-flight global prefetch loads survive the barrier. Trailing memory
// fence keeps post-barrier LDS reads from hoisting above it.
#define BAR_NODRAIN()                                             \
    do {                                                          \
        asm volatile("s_waitcnt lgkmcnt(0)" ::: "memory");        \
        __builtin_amdgcn_s_barrier();                             \
        asm volatile("" ::: "memory");                            \
    } while (0)

// ---- workspace byte layout (ws_size = 384 MiB) ----
// 0        counts[8]
// 64       ntl[1]
// 128      texp[24]
// 256      perm[3072]               -> ends 12544
// 12544    bucket[8*2048]           -> ends 78080
// 78080    zb bf16 [2048*128]       -> ends 602368
// 602368   Hb bf16 [3072*1024]      -> ends 6893824

__global__ __launch_bounds__(256) void route_kernel(const float* __restrict__ z,
                                                    __hip_bfloat16* __restrict__ zb,
                                                    int* counts, int* bucket) {
    __shared__ int lcnt[NEXP];
    __shared__ int gbase[NEXP];
    int t = threadIdx.x;
    if (t < NEXP) lcnt[t] = 0;
    __syncthreads();

    int s = blockIdx.x * 32 + (t >> 3);          // sample
    int li = t & 7;                               // lane-in-sample
    const float* zp = z + (size_t)s * ZD + li * 16;
    float sum = 0.f;
    union { bf16x8 v8; __hip_bfloat16 h[8]; } u0, u1;
#pragma unroll
    for (int i = 0; i < 4; i++) {
        float4 v = ((const float4*)zp)[i];
        sum += floorf(fabsf(v.x) * 1000.0f) + floorf(fabsf(v.y) * 1000.0f) +
               floorf(fabsf(v.z) * 1000.0f) + floorf(fabsf(v.w) * 1000.0f);
        __hip_bfloat16* dst = (i < 2) ? &u0.h[i * 4] : &u1.h[(i - 2) * 4];
        dst[0] = __float2bfloat16(v.x);
        dst[1] = __float2bfloat16(v.y);
        dst[2] = __float2bfloat16(v.z);
        dst[3] = __float2bfloat16(v.w);
    }
    bf16x8* zo = (bf16x8*)(zb + (size_t)s * ZD + li * 16);
    zo[0] = u0.v8;
    zo[1] = u1.v8;

    sum += __shfl_down(sum, 4);
    sum += __shfl_down(sum, 2);
    sum += __shfl_down(sum, 1);
    int e = 0, lpos = 0;
    if (li == 0) {
        e = ((int)sum) & 7;
        lpos = atomicAdd(&lcnt[e], 1);
    }
    __syncthreads();
    if (t < NEXP) gbase[t] = atomicAdd(&counts[t], lcnt[t]);
    __syncthreads();
    if (li == 0) bucket[e * BATCH + gbase[e] + lpos] = s;
}

__global__ void scan_kernel(const int* __restrict__ counts, int* ntl,
                            int* texp, int* perm, const int* __restrict__ bucket) {
    __shared__ int soff[NEXP + 1];
    __shared__ int scnt[NEXP];
    if (threadIdx.x == 0) {
        int o = 0;
        for (int e = 0; e < NEXP; e++) {
            scnt[e] = counts[e];
            soff[e] = o;
            o += (scnt[e] + 127) & ~127;
        }
        soff[NEXP] = o;
        *ntl = o / 128;
    }
    __syncthreads();
    int total = soff[NEXP];
    for (int r = threadIdx.x; r < total; r += blockDim.x) {
        int e = 0;
        while (r >= soff[e + 1]) e++;
        int i = r - soff[e];
        perm[r] = (i < scnt[e]) ? bucket[e * BATCH + i] : -1;
        if ((r & 127) == 0) texp[r / 128] = e;
    }
}

// ---------------- gemm1: 64m x 64n, BK=64, K=128 (2 iters) ----------------
// ~608 blocks. All-thread staging; dbuf; 1 raw barrier/iter; XOR-chunk LDS.
__global__ __launch_bounds__(256, 4) void gemm1_fast(
    const __hip_bfloat16* __restrict__ zb, const float* __restrict__ W1,
    const float* __restrict__ b1, const int* __restrict__ ntl,
    const int* __restrict__ texp, const int* __restrict__ perm,
    __hip_bfloat16* __restrict__ H) {
    int mt = blockIdx.y;                 // 64-row tile index
    if (mt >= 2 * (*ntl)) return;
    int e = texp[mt >> 1];
    int n0 = blockIdx.x * 64;

    __shared__ __align__(16) __hip_bfloat16 As[2][64 * 64];   // 2 x 8 KB
    __shared__ __align__(16) __hip_bfloat16 Bs[2][64 * 64];   // 2 x 8 KB

    int tid = threadIdx.x;
    int lane = tid & 63, wave = tid >> 6;
    int cc = lane & 15, q = lane >> 4;
    int mw = (wave >> 1) * 32, nw = (wave & 1) * 32;

    // A staging: thread t covers rows rg and rg+32, k-chunk sc
    int sc = tid & 7, rg = tid >> 3;     // rg 0..31
    int r0 = perm[mt * 64 + rg];      if (r0 < 0) r0 = 0;
    int r1 = perm[mt * 64 + rg + 32]; if (r1 < 0) r1 = 0;
    const __hip_bfloat16* Ap0 = zb + (size_t)r0 * ZD + sc * 8;
    const __hip_bfloat16* Ap1 = zb + (size_t)r1 * ZD + sc * 8;
    int awb = rg * 64 + (sc ^ (rg & 7)) * 8;   // row rg+32 -> +2048, same xor

    // B staging: bkc = k-chunk, 2 n per thread (float2 loads, 64B segments)
    int bkc = tid & 7, bn2 = (tid >> 3) * 2;   // bn2 0..62
    const float* Bgf = W1 + (size_t)e * ZD * HID + (size_t)(bkc * 8) * HID + n0 + bn2;
    int bwb[2];
#pragma unroll
    for (int j = 0; j < 2; j++)
        bwb[j] = ((bn2 + j) * 8 + (bkc ^ ((bn2 + j) & 7))) * 8;

    int A0 = (mw + cc) * 64, B0 = (nw + cc) * 64;
    int X0 = (q ^ (cc & 7)) * 8, X1 = ((4 + q) ^ (cc & 7)) * 8;

    float bias[2];
#pragma unroll
    for (int j = 0; j < 2; j++) bias[j] = b1[(size_t)e * HID + n0 + nw + j * 16 + cc];

    f32x4 zero4 = {0.f, 0.f, 0.f, 0.f};
    f32x4 acc[2][2];
#pragma unroll
    for (int i = 0; i < 2; i++)
#pragma unroll
        for (int j = 0; j < 2; j++) acc[i][j] = zero4;

    bf16x8 ga0 = *(const bf16x8*)Ap0;
    bf16x8 ga1 = *(const bf16x8*)Ap1;
    float2 braw[8];
#pragma unroll
    for (int i = 0; i < 8; i++) braw[i] = *(const float2*)(Bgf + (size_t)i * HID);

#pragma unroll
    for (int it = 0; it < 2; ++it) {
        __hip_bfloat16* Ac = As[it];
        __hip_bfloat16* Bc = Bs[it];
        union { bf16x8 v8; __hip_bfloat16 h[8]; } gbv[2];
#pragma unroll
        for (int i = 0; i < 8; i++) {
            gbv[0].h[i] = __float2bfloat16(braw[i].x);
            gbv[1].h[i] = __float2bfloat16(braw[i].y);
        }
        *(bf16x8*)(Ac + awb) = ga0;
        *(bf16x8*)(Ac + awb + 2048) = ga1;
#pragma unroll
        for (int j = 0; j < 2; j++) *(bf16x8*)(Bc + bwb[j]) = gbv[j].v8;
        if (it == 0) {
            ga0 = *(const bf16x8*)(Ap0 + 64);
            ga1 = *(const bf16x8*)(Ap1 + 64);
#pragma unroll
            for (int i = 0; i < 8; i++)
                braw[i] = *(const float2*)(Bgf + (size_t)(64 + i) * HID);
        }
        BAR_NODRAIN();
#pragma unroll
        for (int kh = 0; kh < 2; ++kh) {
            int X = kh ? X1 : X0;
            bf16x8 af[2], bfr[2];
#pragma unroll
            for (int i = 0; i < 2; i++) af[i] = *(const bf16x8*)(Ac + A0 + i * 1024 + X);
#pragma unroll
            for (int j = 0; j < 2; j++) bfr[j] = *(const bf16x8*)(Bc + B0 + j * 1024 + X);
#pragma unroll
            for (int i = 0; i < 2; i++)
#pragma unroll
                for (int j = 0; j < 2; j++)
                    acc[i][j] = __builtin_amdgcn_mfma_f32_16x16x32_bf16(af[i], bfr[j],
                                                                        acc[i][j], 0, 0, 0);
        }
    }
#pragma unroll
    for (int i = 0; i < 2; i++)
#pragma unroll
        for (int r = 0; r < 4; r++) {
            int m = mw + i * 16 + q * 4 + r;
            __hip_bfloat16* hp = H + (size_t)(mt * 64 + m) * HID + n0 + nw + cc;
#pragma unroll
            for (int j = 0; j < 2; j++)
                hp[j * 16] = __float2bfloat16(fmaxf(acc[i][j][r] + bias[j], 0.f));
        }
}

// ---------------- gemm2: 128m x 128n, BK=64 (round-6 geometry) ----------------
// Grid (24, MAXTF) = 576 blocks, 2 blocks/CU (64.5 KB LDS). All-thread staging,
// convert deferred past the MFMA phase, ONE raw barrier per phase, 2 LDS
// buffers, distance-2 register prefetch (sets A/B). With the non-draining
// barrier the prefetch loads finally stay in flight across phases.
__global__ __launch_bounds__(256, 2) void gemm2_fast(
    const __hip_bfloat16* __restrict__ H, const float* __restrict__ W2,
    const float* __restrict__ b2, const int* __restrict__ ntl,
    const int* __restrict__ texp, const int* __restrict__ perm,
    float* __restrict__ out) {
    int mt = blockIdx.y;
    if (mt >= *ntl) return;
    int e = texp[mt];
    int n0 = blockIdx.x * 128;

    __shared__ __align__(16) __hip_bfloat16 As[2][128 * 64];   // 2 x 16 KB
    __shared__ __align__(16) __hip_bfloat16 Bs[2][128 * 64];   // 2 x 16 KB
    __shared__ int rows_s[128];

    int tid = threadIdx.x;
    if (tid < 128) rows_s[tid] = perm[mt * 128 + tid];

    int lane = tid & 63, wave = tid >> 6;
    int cc = lane & 15, q = lane >> 4;
    int mw = (wave >> 1) * 64, nw = (wave & 1) * 64;

    // A staging: thread covers rows sr + p*32 (p=0..3), k-chunk sc
    int sr = tid >> 3, sc = tid & 7;
    int awbase = sr * 64 + (sc ^ (sr & 7)) * 8;     // + p*2048
    const __hip_bfloat16* Ag = H + ((size_t)mt * 128 + sr) * HID + sc * 8;

    // B staging: bkc = k-chunk (8 rows), 4 n per thread (float4)
    int bkc = tid & 7, bn = (tid >> 3) * 4;
    const float* Bgf = W2 + (size_t)e * HID * OUTD + (size_t)(bkc * 8) * OUTD + n0 + bn;
    int bwb[4];
#pragma unroll
    for (int j = 0; j < 4; j++)
        bwb[j] = (bn + j) * 64 + ((bkc ^ ((bn + j) & 7))) * 8;

    int A0 = (mw + cc) * 64, B0 = (nw + cc) * 64;
    int X0 = (q ^ (cc & 7)) * 8, X1 = ((4 + q) ^ (cc & 7)) * 8;

    float bias[4];
#pragma unroll
    for (int j = 0; j < 4; j++) bias[j] = b2[(size_t)e * OUTD + n0 + nw + j * 16 + cc];

    f32x4 zero4 = {0.f, 0.f, 0.f, 0.f};
    f32x4 acc[4][4];
#pragma unroll
    for (int i = 0; i < 4; i++)
#pragma unroll
        for (int j = 0; j < 4; j++) acc[i][j] = zero4;

    // Distance-2 prefetch: set A holds k-block (2*itp), set B holds (2*itp+1).
    bf16x8 gaA[4], gaB[4];
    float4 brA[8], brB[8];
#pragma unroll
    for (int p = 0; p < 4; p++) gaA[p] = *(const bf16x8*)(Ag + (size_t)p * 32 * HID);
#pragma unroll
    for (int i = 0; i < 8; i++) brA[i] = *(const float4*)(Bgf + (size_t)i * OUTD);
#pragma unroll
    for (int p = 0; p < 4; p++) gaB[p] = *(const bf16x8*)(Ag + (size_t)p * 32 * HID + 64);
#pragma unroll
    for (int i = 0; i < 8; i++) brB[i] = *(const float4*)(Bgf + (size_t)(64 + i) * OUTD);

    const int NIT = HID / 64;   // 16 (even)
    for (int itp = 0; itp < NIT / 2; ++itp) {
        int kre = itp * 128;                 // reload bases: even -> kre+128, odd -> kre+192
        bool more = (itp < NIT / 2 - 1);

        // ======== even iter (k-block 2*itp): consume set A, LDS buf 0 ========
        {
            union { bf16x8 v8; __hip_bfloat16 h[8]; } gb[4];
#pragma unroll
            for (int i = 0; i < 8; i++) {
                gb[0].h[i] = __float2bfloat16(brA[i].x);
                gb[1].h[i] = __float2bfloat16(brA[i].y);
                gb[2].h[i] = __float2bfloat16(brA[i].z);
                gb[3].h[i] = __float2bfloat16(brA[i].w);
            }
#pragma unroll
            for (int p = 0; p < 4; p++) *(bf16x8*)(As[0] + awbase + p * 2048) = gaA[p];
#pragma unroll
            for (int j = 0; j < 4; j++) *(bf16x8*)(Bs[0] + bwb[j]) = gb[j].v8;
            if (more) {
#pragma unroll
                for (int p = 0; p < 4; p++)
                    gaA[p] = *(const bf16x8*)(Ag + (size_t)p * 32 * HID + kre + 128);
#pragma unroll
                for (int i = 0; i < 8; i++)
                    brA[i] = *(const float4*)(Bgf + (size_t)(kre + 128 + i) * OUTD);
            }
            BAR_NODRAIN();
#pragma unroll
            for (int kh = 0; kh < 2; ++kh) {
                int X = kh ? X1 : X0;
                bf16x8 af[4], bfr[4];
#pragma unroll
                for (int i = 0; i < 4; i++) af[i] = *(const bf16x8*)(As[0] + A0 + i * 1024 + X);
#pragma unroll
                for (int j = 0; j < 4; j++) bfr[j] = *(const bf16x8*)(Bs[0] + B0 + j * 1024 + X);
#pragma unroll
                for (int i = 0; i < 4; i++)
#pragma unroll
                    for (int j = 0; j < 4; j++)
                        acc[i][j] = __builtin_amdgcn_mfma_f32_16x16x32_bf16(af[i], bfr[j],
                                                                            acc[i][j], 0, 0, 0);
            }
        }

        // ======== odd iter (k-block 2*itp+1): consume set B, LDS buf 1 ========
        {
            union { bf16x8 v8; __hip_bfloat16 h[8]; } gb[4];
#pragma unroll
            for (int i = 0; i < 8; i++) {
                gb[0].h[i] = __float2bfloat16(brB[i].x);
                gb[1].h[i] = __float2bfloat16(brB[i].y);
                gb[2].h[i] = __float2bfloat16(brB[i].z);
                gb[3].h[i] = __float2bfloat16(brB[i].w);
            }
#pragma unroll
            for (int p = 0; p < 4; p++) *(bf16x8*)(As[1] + awbase + p * 2048) = gaB[p];
#pragma unroll
            for (int j = 0; j < 4; j++) *(bf16x8*)(Bs[1] + bwb[j]) = gb[j].v8;
            if (more) {
#pragma unroll
                for (int p = 0; p < 4; p++)
                    gaB[p] = *(const bf16x8*)(Ag + (size_t)p * 32 * HID + kre + 192);
#pragma unroll
                for (int i = 0; i < 8; i++)
                    brB[i] = *(const float4*)(Bgf + (size_t)(kre + 192 + i) * OUTD);
            }
            BAR_NODRAIN();
#pragma unroll
            for (int kh = 0; kh < 2; ++kh) {
                int X = kh ? X1 : X0;
                bf16x8 af[4], bfr[4];
#pragma unroll
                for (int i = 0; i < 4; i++) af[i] = *(const bf16x8*)(As[1] + A0 + i * 1024 + X);
#pragma unroll
                for (int j = 0; j < 4; j++) bfr[j] = *(const bf16x8*)(Bs[1] + B0 + j * 1024 + X);
#pragma unroll
                for (int i = 0; i < 4; i++)
#pragma unroll
                    for (int j = 0; j < 4; j++)
                        acc[i][j] = __builtin_amdgcn_mfma_f32_16x16x32_bf16(af[i], bfr[j],
                                                                            acc[i][j], 0, 0, 0);
            }
        }
    }

#pragma unroll
    for (int i = 0; i < 4; i++)
#pragma unroll
        for (int r = 0; r < 4; r++) {
            int m = mw + i * 16 + q * 4 + r;
            int orow = rows_s[m];
            if (orow >= 0) {
                float* op = out + (size_t)orow * OUTD + n0 + nw + cc;
#pragma unroll
                for (int j = 0; j < 4; j++) op[j * 16] = acc[i][j][r] + bias[j];
            }
        }
}

extern "C" void kernel_launch(void* const* d_in, const int* in_sizes, int n_in,
                              void* d_out, int out_size, void* d_ws, size_t ws_size,
                              hipStream_t stream) {
    const float* z  = (const float*)d_in[0];
    const float* W1 = (const float*)d_in[1];
    const float* b1 = (const float*)d_in[2];
    const float* W2 = (const float*)d_in[3];
    const float* b2 = (const float*)d_in[4];
    float* out = (float*)d_out;

    char* ws = (char*)d_ws;
    int* counts = (int*)ws;
    int* ntl    = (int*)(ws + 64);
    int* texp   = (int*)(ws + 128);
    int* perm   = (int*)(ws + 256);
    int* bucket = (int*)(ws + 12544);
    __hip_bfloat16* zb  = (__hip_bfloat16*)(ws + 78080);
    __hip_bfloat16* Hb  = (__hip_bfloat16*)(ws + 602368);

    hipMemsetAsync(counts, 0, 64, stream);
    hipLaunchKernelGGL(route_kernel, dim3(BATCH / 32), dim3(256), 0, stream,
                       z, zb, counts, bucket);
    hipLaunchKernelGGL(scan_kernel, dim3(1), dim3(256), 0, stream,
                       counts, ntl, texp, perm, bucket);
    hipLaunchKernelGGL(gemm1_fast, dim3(HID / 64, 2 * MAXTF), dim3(256), 0, stream,
                       zb, W1, b1, ntl, texp, perm, Hb);
    hipLaunchKernelGGL(gemm2_fast, dim3(OUTD / 128, MAXTF), dim3(256), 0, stream,
                       Hb, W2, b2, ntl, texp, perm, out);
}